// Round 11
// baseline (858.318 us; speedup 1.0000x reference)
//
#include <hip/hip_runtime.h>
#include <hip/hip_bf16.h>
#include <math.h>

#define B_ 2
#define L_ 2048
#define D_ 1024
#define K_ 32
#define M_ 4
#define H_ 32
#define AH_ 4
#define DH_ 28
#define CK_ 4
#define TOTAL_ 2208
#define NPAD_ 2304
#define BL_ (B_*L_)
#define CL_ 16
#define NC_ (L_/CL_)   // 128
#define CTS_ 280       // ct row stride (ushorts)

typedef __attribute__((ext_vector_type(8))) short bf16x8;
typedef __attribute__((ext_vector_type(4))) float f32x4;

static __device__ inline unsigned short f2bu(float f) {
    union { __hip_bfloat16 h; unsigned short u; } cv;
    cv.h = __float2bfloat16(f);
    return cv.u;
}
static __device__ inline float b2f(unsigned short u) {
    union { unsigned short u; __hip_bfloat16 h; } cv;
    cv.u = u;
    return __bfloat162float(cv.h);
}

// direct 4-tap causal conv at position l (identical chain in pass1f & scan_k7
// so recomputed values match bitwise). z is bf16 with row stride NPAD_.
static __device__ inline float convd(const ushort* z, int blbase, int l, int ch,
                                     const float* w4, float bias) {
    float acc = bias;
#pragma unroll
    for (int tap = 0; tap < 4; ++tap) {
        int ls = l - 3 + tap;
        float zv = (ls >= 0) ? b2f(z[(size_t)(blbase + ls) * NPAD_ + ch]) : 0.f;
        acc = fmaf(w4[tap], zv, acc);
    }
    return acc;
}

// ---------- fused prep: x->bf16, W_in^T, Wout^T, W2B, zero cnt ---------------
__global__ __launch_bounds__(256) void prep_all(const float* __restrict__ x,
                                                const float* __restrict__ W_in,
                                                const float* __restrict__ Wout,
                                                const float* __restrict__ Wre,
                                                const float* __restrict__ Wim,
                                                const float* __restrict__ nscale,
                                                ushort* __restrict__ x_bf,
                                                ushort* __restrict__ Wt_in,
                                                ushort* __restrict__ Wt_o,
                                                ushort* __restrict__ W2B,
                                                int* __restrict__ cnt) {
    __shared__ float tile[64][65];
    int bid = blockIdx.x, t = threadIdx.x;
    if (bid < 4096) {
        int i = bid * 256 + t;
        float4 v = ((const float4*)x)[i];
        ushort4 o;
        o.x = f2bu(v.x); o.y = f2bu(v.y); o.z = f2bu(v.z); o.w = f2bu(v.w);
        *(ushort4*)(x_bf + (size_t)i * 4) = o;
        return;
    }
    const float* src; ushort* dst; int Kd, N, n0, k0;
    if (bid < 4096 + 576) {
        int bb = bid - 4096;
        src = W_in; dst = Wt_in; Kd = 1024; N = TOTAL_;
        n0 = (bb % 36) * 64; k0 = (bb / 36) * 64;
    } else if (bid < 4096 + 576 + 256) {
        int bb = bid - 4096 - 576;
        src = Wout; dst = Wt_o; Kd = 1024; N = 1024;
        n0 = (bb % 16) * 64; k0 = (bb / 16) * 64;
    } else if (bid == 4096 + 576 + 256) {
        int ch = t;  // 256
        float ns = nscale[ch];
        for (int ho = 0; ho < 32; ++ho) {
            float w = (ch < 128) ? Wre[ch * 32 + ho] : Wim[(ch - 128) * 32 + ho];
            W2B[ho * 256 + ch] = f2bu(ns * w);
        }
        return;
    } else {
        if (t < 64) cnt[t] = 0;
        return;
    }
#pragma unroll
    for (int i = 0; i < 16; ++i) {
        int idx = t + i * 256;
        int r = idx >> 6, c = idx & 63;
        int gn = n0 + c;
        tile[r][c] = (gn < N) ? src[(size_t)(k0 + r) * N + gn] : 0.f;
    }
    __syncthreads();
#pragma unroll
    for (int i = 0; i < 16; ++i) {
        int idx = t + i * 256;
        int r = idx >> 6, c = idx & 63;
        dst[(size_t)(n0 + r) * Kd + k0 + c] = f2bu(tile[c][r]);
    }
}

// ---------- bf16 MFMA GEMM, 64(M)x128(N) tile --------------------------------
template <bool OUT_BF16>
__global__ __launch_bounds__(256) void gemm_bt64(const ushort* __restrict__ A,
                                                 const ushort* __restrict__ Bt,
                                                 void* __restrict__ Cv,
                                                 int Kd, int ldc) {
    __shared__ __align__(16) ushort SB[192 * 32];
    int tid = threadIdx.x;
    int wave = tid >> 6, lane = tid & 63;
    int quad = lane >> 4, l16 = lane & 15;
    int n0 = blockIdx.x * 128, m0 = blockIdx.y * 64;
    int wm = (wave & 1) * 32, wn = (wave >> 1) * 64;
    f32x4 acc[2][4];
#pragma unroll
    for (int i = 0; i < 2; ++i)
#pragma unroll
        for (int j = 0; j < 4; ++j) acc[i][j] = (f32x4){0.f, 0.f, 0.f, 0.f};

    int swzq = quad ^ (l16 & 3);

    for (int k0 = 0; k0 < Kd; k0 += 32) {
#pragma unroll
        for (int i = 0; i < 3; ++i) {
            int s = i * 256 + tid;
            int row = s >> 2;
            int qg = (s & 3) ^ (row & 3);
            const ushort* g = (row < 64) ? A + (size_t)(m0 + row) * Kd + k0 + qg * 8
                                         : Bt + (size_t)(n0 + row - 64) * Kd + k0 + qg * 8;
            __builtin_amdgcn_global_load_lds((const __attribute__((address_space(1))) void*)g,
                                             (__attribute__((address_space(3))) void*)(SB + (size_t)s * 8),
                                             16, 0, 0);
        }
        __syncthreads();
        bf16x8 af[2], bfr[4];
#pragma unroll
        for (int mi = 0; mi < 2; ++mi)
            af[mi] = *(const bf16x8*)(SB + (size_t)(wm + mi * 16 + l16) * 32 + swzq * 8);
#pragma unroll
        for (int ni = 0; ni < 4; ++ni)
            bfr[ni] = *(const bf16x8*)(SB + (size_t)(64 + wn + ni * 16 + l16) * 32 + swzq * 8);
#pragma unroll
        for (int mi = 0; mi < 2; ++mi)
#pragma unroll
            for (int ni = 0; ni < 4; ++ni)
                acc[mi][ni] = __builtin_amdgcn_mfma_f32_16x16x32_bf16(af[mi], bfr[ni], acc[mi][ni], 0, 0, 0);
        __syncthreads();
    }
#pragma unroll
    for (int mi = 0; mi < 2; ++mi)
#pragma unroll
        for (int ni = 0; ni < 4; ++ni)
#pragma unroll
            for (int r = 0; r < 4; ++r) {
                int gm = m0 + wm + mi * 16 + quad * 4 + r;
                int gn = n0 + wn + ni * 16 + l16;
                if (OUT_BF16)
                    ((ushort*)Cv)[(size_t)gm * ldc + gn] = f2bu(acc[mi][ni][r]);
                else
                    ((float*)Cv)[(size_t)gm * ldc + gn] = acc[mi][ni][r];
            }
}

// ---------- pass1f: precompute + chunk sums + vc MFMA + last-block scan ------
__global__ __launch_bounds__(128) void pass1f(const ushort* __restrict__ z,
                                              const float* __restrict__ mask,
                                              const float* __restrict__ theta_base,
                                              const float* __restrict__ trs_,
                                              const float* __restrict__ dslopes,
                                              const float* __restrict__ aslopes,
                                              const float* __restrict__ sscale_,
                                              const float* __restrict__ conv_w,
                                              const float* __restrict__ conv_b,
                                              const ushort* __restrict__ W2B,
                                              float* __restrict__ cs_re,
                                              float* __restrict__ cs_im,
                                              float* __restrict__ cs_den,
                                              float* __restrict__ vc,
                                              float* __restrict__ ucs,
                                              float* __restrict__ u_prev,
                                              int* __restrict__ cnt) {
    __shared__ __align__(16) ushort ct[CL_ * CTS_];
    __shared__ float theta_s[CL_ * 4];
    __shared__ float pw_s[CL_];
    __shared__ float xv_s[CL_][33];
    __shared__ int lastS;

    int nc = blockIdx.x, k = blockIdx.y, b = blockIdx.z;
    int hm = threadIdx.x;
    int bk = b * K_ + k;
    size_t bkL = (size_t)bk * L_;
    int l0 = nc * CL_;
    int blb = b * L_;
    const float PI3 = 1.04719755119659775f;

    float raw = (k < DH_) ? dslopes[k] : aslopes[k - DH_];
    float slope = log1pf(__expf(raw));

    // --- precompute theta(l,m): threads 0..63 ---
    if (hm < 64) {
        int li = hm >> 2, m = hm & 3;
        int l = l0 + li;
        int cth = 2 * D_ + K_ + k * M_ + m;
        float wt[4];
#pragma unroll
        for (int t = 0; t < 4; ++t) wt[t] = conv_w[t * TOTAL_ + cth];
        float tr = convd(z, blb, l, cth, wt, conv_b[cth]);
        float td = tr / (1.f + fabsf(tr));
        theta_s[li * 4 + m] = theta_base[k * M_ + m] + trs_[k] * (td * PI3);
    }
    // --- precompute pw(l): threads 64..79 ---
    if (hm >= 64 && hm < 64 + CL_) {
        int li = hm - 64;
        int l = l0 + li;
        int csc = 2 * D_ + k;
        float wsv[4];
#pragma unroll
        for (int t = 0; t < 4; ++t) wsv[t] = conv_w[t * TOTAL_ + csc];
        float mval = mask[blb + l];
        float s_raw = convd(z, blb, l, csc, wsv, conv_b[csc]) * mval;
        float arg = fminf(fmaxf(sscale_[k] * s_raw, -20.f), 20.f);
        float p = __expf(arg) * mval;
        float tw = (k < DH_) ? __expf(-slope * (float)(L_ - 1 - l)) : __expf(-slope * (float)l);
        pw_s[li] = p * tw;
    }
    // --- precompute xv(l,h): all 128 threads, 4 l's each ---
    {
        int h = hm & 31, lset = hm >> 5;
        int cxv = k * H_ + h;
        float wxv[4];
#pragma unroll
        for (int t = 0; t < 4; ++t) wxv[t] = conv_w[t * TOTAL_ + cxv];
        float bxv = conv_b[cxv];
#pragma unroll
        for (int j = 0; j < 4; ++j) {
            int li = lset * 4 + j;
            int l = l0 + li;
            float xv = convd(z, blb, l, cxv, wxv, bxv) * mask[blb + l];
            xv_s[li][h] = xv;
        }
    }
    __syncthreads();

    // --- main loop: contributions + chunk sums ---
    int h = hm >> 2, m = hm & 3;
    float are = 0.f, aim = 0.f;
#pragma unroll
    for (int i = 0; i < CL_; ++i) {
        float phi = xv_s[i][h] * theta_s[i * 4 + m];
        float pw = pw_s[i];
        float sv = __sinf(phi), cv = __cosf(phi);
        unsigned short cu_re = f2bu(pw * cv);
        unsigned short cu_im = f2bu(pw * sv);
        are += b2f(cu_re); aim += b2f(cu_im);
        ct[i * CTS_ + hm] = cu_re;
        ct[i * CTS_ + 128 + hm] = cu_im;
    }
    size_t o = ((size_t)(bk * NC_ + nc)) * 128 + hm;
    cs_re[o] = are;
    cs_im[o] = aim;
    if (hm == 0) {
        float aden = 0.f;
#pragma unroll
        for (int i = 0; i < CL_; ++i) aden += pw_s[i];
        cs_den[bk * NC_ + nc] = aden;
    }
    __syncthreads();
    // --- vc = C_chunk(16x256) @ W''(256x32) via MFMA; wave w -> hout tile w ---
    int wave = hm >> 6, lane = hm & 63;
    int quad = lane >> 4, l16 = lane & 15;
    f32x4 acc = (f32x4){0.f, 0.f, 0.f, 0.f};
#pragma unroll
    for (int ks = 0; ks < 8; ++ks) {
        bf16x8 af = *(const bf16x8*)(ct + (size_t)l16 * CTS_ + ks * 32 + quad * 8);
        bf16x8 bfr = *(const bf16x8*)(W2B + (size_t)(wave * 16 + l16) * 256 + ks * 32 + quad * 8);
        acc = __builtin_amdgcn_mfma_f32_16x16x32_bf16(af, bfr, acc, 0, 0, 0);
    }
    size_t vbase = (bkL + l0) * 32;
#pragma unroll
    for (int r = 0; r < 4; ++r) {
        int rowv = quad * 4 + r;
        vc[vbase + (size_t)rowv * 32 + wave * 16 + l16] = acc[r];
    }
    float part = acc[0] + acc[1] + acc[2] + acc[3];
    part += __shfl_xor(part, 16, 64);
    part += __shfl_xor(part, 32, 64);
    if (quad == 0) ucs[((size_t)(bk * NC_ + nc)) * 32 + wave * 16 + l16] = part;

    // --- last block per bk performs the chunk-prefix scans (replaces scan2) --
    __threadfence();
    if (hm == 0) {
        int old = __hip_atomic_fetch_add(&cnt[bk], 1, __ATOMIC_ACQ_REL,
                                         __HIP_MEMORY_SCOPE_AGENT);
        lastS = (old == NC_ - 1) ? 1 : 0;
    }
    __syncthreads();
    if (lastS) {
        for (int ch = hm; ch < 257; ch += 128) {
            float* base;
            int stride;
            if (ch < 128) { base = cs_re + (size_t)bk * NC_ * 128 + ch; stride = 128; }
            else if (ch < 256) { base = cs_im + (size_t)bk * NC_ * 128 + (ch - 128); stride = 128; }
            else { base = cs_den + (size_t)bk * NC_; stride = 1; }
            float run = 0.f;
#pragma unroll 4
            for (int i = 0; i < NC_; ++i) {
                float v = base[(size_t)i * stride];
                base[(size_t)i * stride] = run;
                run += v;
            }
        }
        if (hm < 32) {
            float run = 0.f;
#pragma unroll 8
            for (int ncq = 0; ncq < NC_; ++ncq) {
                size_t oo = ((size_t)bk * NC_ + ncq) * 32 + hm;
                float v = ucs[oo];
                u_prev[oo] = run;
                run += v;
            }
        }
    }
}

// ---------- scan_k7: precompute + snapshot scan + deferred reduces + store ---
__global__ __launch_bounds__(64) void scan_k7(const ushort* __restrict__ z,
                                              const float* __restrict__ mask,
                                              const float* __restrict__ theta_base,
                                              const float* __restrict__ trs_,
                                              const float* __restrict__ dslopes,
                                              const float* __restrict__ aslopes,
                                              const float* __restrict__ sscale_,
                                              const float* __restrict__ conv_w,
                                              const float* __restrict__ conv_b,
                                              const float* __restrict__ cs_re,
                                              const float* __restrict__ cs_im,
                                              const float* __restrict__ cs_den,
                                              const float* __restrict__ u_prev,
                                              const float* __restrict__ vc,
                                              ushort* __restrict__ gq) {
    __shared__ float theta_s[CL_ * 4];
    __shared__ float pw_s[CL_];
    __shared__ float xv_s[CL_][33];
    __shared__ float gate_s[CL_][33];

    int nc = blockIdx.x, k = blockIdx.y, b = blockIdx.z;
    int lane = threadIdx.x;
    int bk = b * K_ + k;
    size_t bkL = (size_t)bk * L_;
    int l0 = nc * CL_;
    int blb = b * L_;
    const float PI3 = 1.04719755119659775f;

    float raw = (k < DH_) ? dslopes[k] : aslopes[k - DH_];
    float slope = log1pf(__expf(raw));

    // --- precompute theta(l,m): identical chain to pass1f ---
    {
        int li = lane >> 2, m = lane & 3;
        int l = l0 + li;
        int cth = 2 * D_ + K_ + k * M_ + m;
        float wt[4];
#pragma unroll
        for (int t = 0; t < 4; ++t) wt[t] = conv_w[t * TOTAL_ + cth];
        float tr = convd(z, blb, l, cth, wt, conv_b[cth]);
        float td = tr / (1.f + fabsf(tr));
        theta_s[li * 4 + m] = theta_base[k * M_ + m] + trs_[k] * (td * PI3);
    }
    // --- precompute pw(l): lanes 0..15, identical chain ---
    if (lane < CL_) {
        int l = l0 + lane;
        int csc = 2 * D_ + k;
        float wsv[4];
#pragma unroll
        for (int t = 0; t < 4; ++t) wsv[t] = conv_w[t * TOTAL_ + csc];
        float mval = mask[blb + l];
        float s_raw = convd(z, blb, l, csc, wsv, conv_b[csc]) * mval;
        float arg = fminf(fmaxf(sscale_[k] * s_raw, -20.f), 20.f);
        float p = __expf(arg) * mval;
        float tw = (k < DH_) ? __expf(-slope * (float)(L_ - 1 - l)) : __expf(-slope * (float)l);
        pw_s[lane] = p * tw;
    }
    // --- precompute xv(l,h) and gate(l,hout): 8 l's per lane ---
    {
        int h = lane & 31, lset = lane >> 5;
        int cxv = k * H_ + h;
        int cg = D_ + k * H_ + h;
        float wxv[4], wg[4];
#pragma unroll
        for (int t = 0; t < 4; ++t) {
            wxv[t] = conv_w[t * TOTAL_ + cxv];
            wg[t] = conv_w[t * TOTAL_ + cg];
        }
        float bxv = conv_b[cxv], bg = conv_b[cg];
#pragma unroll
        for (int j = 0; j < 8; ++j) {
            int li = lset * 8 + j;
            int l = l0 + li;
            float xv = convd(z, blb, l, cxv, wxv, bxv) * mask[blb + l];
            xv_s[li][h] = xv;
            float gp = convd(z, blb, l, cg, wg, bg);
            gate_s[li][h] = gp / (1.f + __expf(-gp));
        }
    }
    __syncthreads();

    int h0 = lane >> 2, h1 = 16 + (lane >> 2), m = lane & 3;
    int hout = lane & 31;

    size_t o = ((size_t)(bk * NC_ + nc)) * 128;
    float are0 = cs_re[o + lane];
    float are1 = cs_re[o + 64 + lane];
    float aim0 = cs_im[o + lane];
    float aim1 = cs_im[o + 64 + lane];
    float den = cs_den[bk * NC_ + nc];
    float u = u_prev[((size_t)(bk * NC_ + nc)) * 32 + hout];

    // --- phase A: serial accumulate, per-lane s snapshots (no cross-lane) ---
    float sloc[CL_];
#pragma unroll
    for (int i = 0; i < CL_; ++i) {
        float th = theta_s[i * 4 + m];
        float pw = pw_s[i];
        float phi0 = xv_s[i][h0] * th;
        float phi1 = xv_s[i][h1] * th;
        float s0 = __sinf(phi0), cv0 = __cosf(phi0);
        float s1 = __sinf(phi1), cv1 = __cosf(phi1);
        float cre0 = b2f(f2bu(pw * cv0)), cim0 = b2f(f2bu(pw * s0));
        float cre1 = b2f(f2bu(pw * cv1)), cim1 = b2f(f2bu(pw * s1));
        are0 += cre0; aim0 += cim0; are1 += cre1; aim1 += cim1;
        sloc[i] = are0 * are0 + are1 * are1 + aim0 * aim0 + aim1 * aim1;
    }
    // --- phase B: 16 independent cross-lane reductions (pipelined) ---
#pragma unroll
    for (int i = 0; i < CL_; ++i) {
#pragma unroll
        for (int off = 32; off; off >>= 1) sloc[i] += __shfl_xor(sloc[i], off, 64);
    }
    // --- phase C: den/u chains + gate + store ---
#pragma unroll
    for (int i = 0; i < CL_; ++i) {
        int l = l0 + i;
        den += pw_s[i];
        float inv = 1.f / fmaxf(den, 1e-4f);
        float rsq = rsqrtf(inv * inv * sloc[i] * (1.0f / 256.0f) + 1e-5f);
        u += vc[(bkL + l) * 32 + hout];
        float gv = inv * rsq * u * gate_s[i][hout];
        if (lane < 32) gq[(size_t)(blb + l) * D_ + k * H_ + hout] = f2bu(gv);
    }
}

extern "C" void kernel_launch(void* const* d_in, const int* in_sizes, int n_in,
                              void* d_out, int out_size, void* d_ws, size_t ws_size,
                              hipStream_t stream) {
    const float* x = (const float*)d_in[0];
    const float* mask = (const float*)d_in[1];
    const float* W_in = (const float*)d_in[2];
    const float* conv_w = (const float*)d_in[3];
    const float* conv_b = (const float*)d_in[4];
    const float* theta_base = (const float*)d_in[5];
    const float* trs = (const float*)d_in[6];
    const float* dsl = (const float*)d_in[7];
    const float* asl = (const float*)d_in[8];
    const float* ssc = (const float*)d_in[9];
    const float* nsc = (const float*)d_in[10];
    const float* Wre = (const float*)d_in[11];
    const float* Wim = (const float*)d_in[12];
    const float* Wout = (const float*)d_in[13];
    float* out = (float*)d_out;

    char* ws = (char*)d_ws;
    ushort* z     = (ushort*)(ws);                   // 18,874,368
    ushort* x_bf  = (ushort*)(ws + 18874368ULL);     // 8,388,608
    ushort* Wt_in = (ushort*)(ws + 27262976ULL);     // 4,718,592
    ushort* Wt_o  = (ushort*)(ws + 31981568ULL);     // 2,097,152
    ushort* W2B   = (ushort*)(ws + 34078720ULL);     // 16,384
    float* vc     = (float*)(ws + 34095104ULL);      // 16,777,216
    float* cs_re  = (float*)(ws + 50872320ULL);      // 4,194,304
    float* cs_im  = (float*)(ws + 55066624ULL);      // 4,194,304
    float* cs_den = (float*)(ws + 59260928ULL);      // 32,768
    float* ucs    = (float*)(ws + 59293696ULL);      // 1,048,576
    float* u_prev = (float*)(ws + 60342272ULL);      // 1,048,576
    ushort* gq    = (ushort*)(ws + 61390848ULL);     // 8,388,608
    int*   cnt    = (int*)(ws + 69779456ULL);        // 256

    prep_all<<<4096 + 576 + 256 + 2, 256, 0, stream>>>(x, W_in, Wout, Wre, Wim, nsc,
                                                       x_bf, Wt_in, Wt_o, W2B, cnt);
    gemm_bt64<true><<<dim3(NPAD_ / 128, BL_ / 64), 256, 0, stream>>>(x_bf, Wt_in, z, 1024, NPAD_);
    pass1f<<<dim3(NC_, K_, B_), 128, 0, stream>>>(z, mask, theta_base, trs, dsl, asl, ssc,
                                                  conv_w, conv_b, W2B,
                                                  cs_re, cs_im, cs_den, vc, ucs, u_prev, cnt);
    scan_k7<<<dim3(NC_, K_, B_), 64, 0, stream>>>(z, mask, theta_base, trs, dsl, asl, ssc,
                                                  conv_w, conv_b, cs_re, cs_im, cs_den,
                                                  u_prev, vc, gq);
    gemm_bt64<false><<<dim3(1024 / 128, BL_ / 64), 256, 0, stream>>>(gq, Wt_o, out, 1024, 1024);
}

// Round 12
// 263.199 us; speedup vs baseline: 3.2611x; 3.2611x over previous
//
#include <hip/hip_runtime.h>
#include <hip/hip_bf16.h>
#include <math.h>

#define B_ 2
#define L_ 2048
#define D_ 1024
#define K_ 32
#define M_ 4
#define H_ 32
#define AH_ 4
#define DH_ 28
#define CK_ 4
#define TOTAL_ 2208
#define NPAD_ 2304
#define BL_ (B_*L_)
#define CL_ 16
#define NC_ (L_/CL_)   // 128
#define CTS_ 280       // ct row stride (ushorts)

typedef __attribute__((ext_vector_type(8))) short bf16x8;
typedef __attribute__((ext_vector_type(8))) unsigned short u16x8;
typedef __attribute__((ext_vector_type(4))) float f32x4;

static __device__ inline unsigned short f2bu(float f) {
    union { __hip_bfloat16 h; unsigned short u; } cv;
    cv.h = __float2bfloat16(f);
    return cv.u;
}
static __device__ inline float b2f(unsigned short u) {
    union { unsigned short u; __hip_bfloat16 h; } cv;
    cv.u = u;
    return __bfloat162float(cv.h);
}

// direct 4-tap causal conv at position l (identical chain in pass1f & scan_k7
// so recomputed values match bitwise). z is bf16 with row stride NPAD_.
static __device__ inline float convd(const ushort* z, int blbase, int l, int ch,
                                     const float* w4, float bias) {
    float acc = bias;
#pragma unroll
    for (int tap = 0; tap < 4; ++tap) {
        int ls = l - 3 + tap;
        float zv = (ls >= 0) ? b2f(z[(size_t)(blbase + ls) * NPAD_ + ch]) : 0.f;
        acc = fmaf(w4[tap], zv, acc);
    }
    return acc;
}

// ---------- prep: W_in^T, Wout^T, W2B (weights only; x handled in gemm1) -----
__global__ __launch_bounds__(256) void prep_all(const float* __restrict__ W_in,
                                                const float* __restrict__ Wout,
                                                const float* __restrict__ Wre,
                                                const float* __restrict__ Wim,
                                                const float* __restrict__ nscale,
                                                ushort* __restrict__ Wt_in,
                                                ushort* __restrict__ Wt_o,
                                                ushort* __restrict__ W2B) {
    __shared__ float tile[64][65];
    int bid = blockIdx.x, t = threadIdx.x;
    const float* src; ushort* dst; int Kd, N, n0, k0;
    if (bid < 576) {
        src = W_in; dst = Wt_in; Kd = 1024; N = TOTAL_;
        n0 = (bid % 36) * 64; k0 = (bid / 36) * 64;
    } else if (bid < 576 + 256) {
        int bb = bid - 576;
        src = Wout; dst = Wt_o; Kd = 1024; N = 1024;
        n0 = (bb % 16) * 64; k0 = (bb / 16) * 64;
    } else {
        int ch = t;  // 256
        float ns = nscale[ch];
        for (int ho = 0; ho < 32; ++ho) {
            float w = (ch < 128) ? Wre[ch * 32 + ho] : Wim[(ch - 128) * 32 + ho];
            W2B[ho * 256 + ch] = f2bu(ns * w);
        }
        return;
    }
#pragma unroll
    for (int i = 0; i < 16; ++i) {
        int idx = t + i * 256;
        int r = idx >> 6, c = idx & 63;
        int gn = n0 + c;
        tile[r][c] = (gn < N) ? src[(size_t)(k0 + r) * N + gn] : 0.f;
    }
    __syncthreads();
#pragma unroll
    for (int i = 0; i < 16; ++i) {
        int idx = t + i * 256;
        int r = idx >> 6, c = idx & 63;
        dst[(size_t)(n0 + r) * Kd + k0 + c] = f2bu(tile[c][r]);
    }
}

// ---------- gemm1: A fp32 (converted in-kernel), B bf16^T, out bf16 ----------
// 64(M)x128(N) tile, BK=32, same swizzled LDS layout as gemm_bt64.
__global__ __launch_bounds__(256) void gemm_f32a(const float* __restrict__ A,
                                                 const ushort* __restrict__ Bt,
                                                 ushort* __restrict__ C,
                                                 int Kd, int ldc) {
    __shared__ __align__(16) ushort SB[192 * 32];
    int tid = threadIdx.x;
    int wave = tid >> 6, lane = tid & 63;
    int quad = lane >> 4, l16 = lane & 15;
    int n0 = blockIdx.x * 128, m0 = blockIdx.y * 64;
    int wm = (wave & 1) * 32, wn = (wave >> 1) * 64;
    f32x4 acc[2][4];
#pragma unroll
    for (int i = 0; i < 2; ++i)
#pragma unroll
        for (int j = 0; j < 4; ++j) acc[i][j] = (f32x4){0.f, 0.f, 0.f, 0.f};

    int swzq = quad ^ (l16 & 3);

    for (int k0 = 0; k0 < Kd; k0 += 32) {
        // B staging: async global->LDS (rows 64..191)
#pragma unroll
        for (int i = 0; i < 2; ++i) {
            int s = 256 + i * 256 + tid;
            int row = s >> 2;
            int qg = (s & 3) ^ (row & 3);
            const ushort* g = Bt + (size_t)(n0 + row - 64) * Kd + k0 + qg * 8;
            __builtin_amdgcn_global_load_lds((const __attribute__((address_space(1))) void*)g,
                                             (__attribute__((address_space(3))) void*)(SB + (size_t)s * 8),
                                             16, 0, 0);
        }
        // A staging: fp32 load + convert + ds_write (rows 0..63)
        {
            int s = tid;
            int row = s >> 2;
            int qg = (s & 3) ^ (row & 3);
            const float* ga = A + (size_t)(m0 + row) * Kd + k0 + qg * 8;
            float4 v0 = *(const float4*)ga;
            float4 v1 = *(const float4*)(ga + 4);
            u16x8 pk;
            pk[0] = f2bu(v0.x); pk[1] = f2bu(v0.y); pk[2] = f2bu(v0.z); pk[3] = f2bu(v0.w);
            pk[4] = f2bu(v1.x); pk[5] = f2bu(v1.y); pk[6] = f2bu(v1.z); pk[7] = f2bu(v1.w);
            *(u16x8*)(SB + (size_t)s * 8) = pk;
        }
        __syncthreads();
        bf16x8 af[2], bfr[4];
#pragma unroll
        for (int mi = 0; mi < 2; ++mi)
            af[mi] = *(const bf16x8*)(SB + (size_t)(wm + mi * 16 + l16) * 32 + swzq * 8);
#pragma unroll
        for (int ni = 0; ni < 4; ++ni)
            bfr[ni] = *(const bf16x8*)(SB + (size_t)(64 + wn + ni * 16 + l16) * 32 + swzq * 8);
#pragma unroll
        for (int mi = 0; mi < 2; ++mi)
#pragma unroll
            for (int ni = 0; ni < 4; ++ni)
                acc[mi][ni] = __builtin_amdgcn_mfma_f32_16x16x32_bf16(af[mi], bfr[ni], acc[mi][ni], 0, 0, 0);
        __syncthreads();
    }
#pragma unroll
    for (int mi = 0; mi < 2; ++mi)
#pragma unroll
        for (int ni = 0; ni < 4; ++ni)
#pragma unroll
            for (int r = 0; r < 4; ++r) {
                int gm = m0 + wm + mi * 16 + quad * 4 + r;
                int gn = n0 + wn + ni * 16 + l16;
                C[(size_t)gm * ldc + gn] = f2bu(acc[mi][ni][r]);
            }
}

// ---------- gemm2: bf16 A and B^T, out fp32 ----------------------------------
__global__ __launch_bounds__(256) void gemm_bt64(const ushort* __restrict__ A,
                                                 const ushort* __restrict__ Bt,
                                                 float* __restrict__ C,
                                                 int Kd, int ldc) {
    __shared__ __align__(16) ushort SB[192 * 32];
    int tid = threadIdx.x;
    int wave = tid >> 6, lane = tid & 63;
    int quad = lane >> 4, l16 = lane & 15;
    int n0 = blockIdx.x * 128, m0 = blockIdx.y * 64;
    int wm = (wave & 1) * 32, wn = (wave >> 1) * 64;
    f32x4 acc[2][4];
#pragma unroll
    for (int i = 0; i < 2; ++i)
#pragma unroll
        for (int j = 0; j < 4; ++j) acc[i][j] = (f32x4){0.f, 0.f, 0.f, 0.f};

    int swzq = quad ^ (l16 & 3);

    for (int k0 = 0; k0 < Kd; k0 += 32) {
#pragma unroll
        for (int i = 0; i < 3; ++i) {
            int s = i * 256 + tid;
            int row = s >> 2;
            int qg = (s & 3) ^ (row & 3);
            const ushort* g = (row < 64) ? A + (size_t)(m0 + row) * Kd + k0 + qg * 8
                                         : Bt + (size_t)(n0 + row - 64) * Kd + k0 + qg * 8;
            __builtin_amdgcn_global_load_lds((const __attribute__((address_space(1))) void*)g,
                                             (__attribute__((address_space(3))) void*)(SB + (size_t)s * 8),
                                             16, 0, 0);
        }
        __syncthreads();
        bf16x8 af[2], bfr[4];
#pragma unroll
        for (int mi = 0; mi < 2; ++mi)
            af[mi] = *(const bf16x8*)(SB + (size_t)(wm + mi * 16 + l16) * 32 + swzq * 8);
#pragma unroll
        for (int ni = 0; ni < 4; ++ni)
            bfr[ni] = *(const bf16x8*)(SB + (size_t)(64 + wn + ni * 16 + l16) * 32 + swzq * 8);
#pragma unroll
        for (int mi = 0; mi < 2; ++mi)
#pragma unroll
            for (int ni = 0; ni < 4; ++ni)
                acc[mi][ni] = __builtin_amdgcn_mfma_f32_16x16x32_bf16(af[mi], bfr[ni], acc[mi][ni], 0, 0, 0);
        __syncthreads();
    }
#pragma unroll
    for (int mi = 0; mi < 2; ++mi)
#pragma unroll
        for (int ni = 0; ni < 4; ++ni)
#pragma unroll
            for (int r = 0; r < 4; ++r) {
                int gm = m0 + wm + mi * 16 + quad * 4 + r;
                int gn = n0 + wn + ni * 16 + l16;
                C[(size_t)gm * ldc + gn] = acc[mi][ni][r];
            }
}

// ---------- pass1f: LDS precompute (theta/pw/xv) + chunk sums + vc MFMA ------
__global__ __launch_bounds__(128) void pass1f(const ushort* __restrict__ z,
                                              const float* __restrict__ mask,
                                              const float* __restrict__ theta_base,
                                              const float* __restrict__ trs_,
                                              const float* __restrict__ dslopes,
                                              const float* __restrict__ aslopes,
                                              const float* __restrict__ sscale_,
                                              const float* __restrict__ conv_w,
                                              const float* __restrict__ conv_b,
                                              const ushort* __restrict__ W2B,
                                              float* __restrict__ cs_re,
                                              float* __restrict__ cs_im,
                                              float* __restrict__ cs_den,
                                              float* __restrict__ vc,
                                              float* __restrict__ ucs) {
    __shared__ __align__(16) ushort ct[CL_ * CTS_];
    __shared__ float theta_s[CL_ * 4];
    __shared__ float pw_s[CL_];
    __shared__ float xv_s[CL_][33];

    int nc = blockIdx.x, k = blockIdx.y, b = blockIdx.z;
    int hm = threadIdx.x;
    int bk = b * K_ + k;
    size_t bkL = (size_t)bk * L_;
    int l0 = nc * CL_;
    int blb = b * L_;
    const float PI3 = 1.04719755119659775f;

    float raw = (k < DH_) ? dslopes[k] : aslopes[k - DH_];
    float slope = log1pf(__expf(raw));

    if (hm < 64) {
        int li = hm >> 2, m = hm & 3;
        int l = l0 + li;
        int cth = 2 * D_ + K_ + k * M_ + m;
        float wt[4];
#pragma unroll
        for (int t = 0; t < 4; ++t) wt[t] = conv_w[t * TOTAL_ + cth];
        float tr = convd(z, blb, l, cth, wt, conv_b[cth]);
        float td = tr / (1.f + fabsf(tr));
        theta_s[li * 4 + m] = theta_base[k * M_ + m] + trs_[k] * (td * PI3);
    }
    if (hm >= 64 && hm < 64 + CL_) {
        int li = hm - 64;
        int l = l0 + li;
        int csc = 2 * D_ + k;
        float wsv[4];
#pragma unroll
        for (int t = 0; t < 4; ++t) wsv[t] = conv_w[t * TOTAL_ + csc];
        float mval = mask[blb + l];
        float s_raw = convd(z, blb, l, csc, wsv, conv_b[csc]) * mval;
        float arg = fminf(fmaxf(sscale_[k] * s_raw, -20.f), 20.f);
        float p = __expf(arg) * mval;
        float tw = (k < DH_) ? __expf(-slope * (float)(L_ - 1 - l)) : __expf(-slope * (float)l);
        pw_s[li] = p * tw;
    }
    {
        int h = hm & 31, lset = hm >> 5;
        int cxv = k * H_ + h;
        float wxv[4];
#pragma unroll
        for (int t = 0; t < 4; ++t) wxv[t] = conv_w[t * TOTAL_ + cxv];
        float bxv = conv_b[cxv];
#pragma unroll
        for (int j = 0; j < 4; ++j) {
            int li = lset * 4 + j;
            int l = l0 + li;
            float xv = convd(z, blb, l, cxv, wxv, bxv) * mask[blb + l];
            xv_s[li][h] = xv;
        }
    }
    __syncthreads();

    int h = hm >> 2, m = hm & 3;
    float are = 0.f, aim = 0.f;
#pragma unroll
    for (int i = 0; i < CL_; ++i) {
        float phi = xv_s[i][h] * theta_s[i * 4 + m];
        float pw = pw_s[i];
        float sv = __sinf(phi), cv = __cosf(phi);
        unsigned short cu_re = f2bu(pw * cv);
        unsigned short cu_im = f2bu(pw * sv);
        are += b2f(cu_re); aim += b2f(cu_im);
        ct[i * CTS_ + hm] = cu_re;
        ct[i * CTS_ + 128 + hm] = cu_im;
    }
    size_t o = ((size_t)(bk * NC_ + nc)) * 128 + hm;
    cs_re[o] = are;
    cs_im[o] = aim;
    if (hm == 0) {
        float aden = 0.f;
#pragma unroll
        for (int i = 0; i < CL_; ++i) aden += pw_s[i];
        cs_den[bk * NC_ + nc] = aden;
    }
    __syncthreads();
    int wave = hm >> 6, lane = hm & 63;
    int quad = lane >> 4, l16 = lane & 15;
    f32x4 acc = (f32x4){0.f, 0.f, 0.f, 0.f};
#pragma unroll
    for (int ks = 0; ks < 8; ++ks) {
        bf16x8 af = *(const bf16x8*)(ct + (size_t)l16 * CTS_ + ks * 32 + quad * 8);
        bf16x8 bfr = *(const bf16x8*)(W2B + (size_t)(wave * 16 + l16) * 256 + ks * 32 + quad * 8);
        acc = __builtin_amdgcn_mfma_f32_16x16x32_bf16(af, bfr, acc, 0, 0, 0);
    }
    size_t vbase = (bkL + l0) * 32;
#pragma unroll
    for (int r = 0; r < 4; ++r) {
        int rowv = quad * 4 + r;
        vc[vbase + (size_t)rowv * 32 + wave * 16 + l16] = acc[r];
    }
    float part = acc[0] + acc[1] + acc[2] + acc[3];
    part += __shfl_xor(part, 16, 64);
    part += __shfl_xor(part, 32, 64);
    if (quad == 0) ucs[((size_t)(bk * NC_ + nc)) * 32 + wave * 16 + l16] = part;
}

// ---------- scan2: fused pass2 (cs exclusive scan) + u_prev scan -------------
__global__ void scan2(float* cs_re, float* cs_im, float* cs_den,
                      const float* __restrict__ ucs, float* __restrict__ u_prev) {
    int bid = blockIdx.x, tid = threadIdx.x;
    if (bid < 65) {
        int seq = bid * 256 + tid;
        if (seq >= B_ * K_ * 257) return;
        int bk = seq / 257;
        int ch = seq % 257;
        float* base;
        int stride;
        if (ch < 128) { base = cs_re + (size_t)bk * NC_ * 128 + ch; stride = 128; }
        else if (ch < 256) { base = cs_im + (size_t)bk * NC_ * 128 + (ch - 128); stride = 128; }
        else { base = cs_den + (size_t)bk * NC_; stride = 1; }
        float run = 0.f;
#pragma unroll 4
        for (int i = 0; i < NC_; ++i) {
            float v = base[(size_t)i * stride];
            base[(size_t)i * stride] = run;
            run += v;
        }
    } else {
        int idx = (bid - 65) * 256 + tid;  // 0..2047
        int hout = idx & 31;
        int bk = idx >> 5;
        float run = 0.f;
#pragma unroll 8
        for (int nc = 0; nc < NC_; ++nc) {
            size_t o = ((size_t)bk * NC_ + nc) * 32 + hout;
            float v = ucs[o];
            u_prev[o] = run;
            run += v;
        }
    }
}

// ---------- scan_k7: precompute + snapshot scan + deferred reduces + store ---
__global__ __launch_bounds__(64) void scan_k7(const ushort* __restrict__ z,
                                              const float* __restrict__ mask,
                                              const float* __restrict__ theta_base,
                                              const float* __restrict__ trs_,
                                              const float* __restrict__ dslopes,
                                              const float* __restrict__ aslopes,
                                              const float* __restrict__ sscale_,
                                              const float* __restrict__ conv_w,
                                              const float* __restrict__ conv_b,
                                              const float* __restrict__ cs_re,
                                              const float* __restrict__ cs_im,
                                              const float* __restrict__ cs_den,
                                              const float* __restrict__ u_prev,
                                              const float* __restrict__ vc,
                                              ushort* __restrict__ gq) {
    __shared__ float theta_s[CL_ * 4];
    __shared__ float pw_s[CL_];
    __shared__ float xv_s[CL_][33];
    __shared__ float gate_s[CL_][33];

    int nc = blockIdx.x, k = blockIdx.y, b = blockIdx.z;
    int lane = threadIdx.x;
    int bk = b * K_ + k;
    size_t bkL = (size_t)bk * L_;
    int l0 = nc * CL_;
    int blb = b * L_;
    const float PI3 = 1.04719755119659775f;

    float raw = (k < DH_) ? dslopes[k] : aslopes[k - DH_];
    float slope = log1pf(__expf(raw));

    {
        int li = lane >> 2, m = lane & 3;
        int l = l0 + li;
        int cth = 2 * D_ + K_ + k * M_ + m;
        float wt[4];
#pragma unroll
        for (int t = 0; t < 4; ++t) wt[t] = conv_w[t * TOTAL_ + cth];
        float tr = convd(z, blb, l, cth, wt, conv_b[cth]);
        float td = tr / (1.f + fabsf(tr));
        theta_s[li * 4 + m] = theta_base[k * M_ + m] + trs_[k] * (td * PI3);
    }
    if (lane < CL_) {
        int l = l0 + lane;
        int csc = 2 * D_ + k;
        float wsv[4];
#pragma unroll
        for (int t = 0; t < 4; ++t) wsv[t] = conv_w[t * TOTAL_ + csc];
        float mval = mask[blb + l];
        float s_raw = convd(z, blb, l, csc, wsv, conv_b[csc]) * mval;
        float arg = fminf(fmaxf(sscale_[k] * s_raw, -20.f), 20.f);
        float p = __expf(arg) * mval;
        float tw = (k < DH_) ? __expf(-slope * (float)(L_ - 1 - l)) : __expf(-slope * (float)l);
        pw_s[lane] = p * tw;
    }
    {
        int h = lane & 31, lset = lane >> 5;
        int cxv = k * H_ + h;
        int cg = D_ + k * H_ + h;
        float wxv[4], wg[4];
#pragma unroll
        for (int t = 0; t < 4; ++t) {
            wxv[t] = conv_w[t * TOTAL_ + cxv];
            wg[t] = conv_w[t * TOTAL_ + cg];
        }
        float bxv = conv_b[cxv], bg = conv_b[cg];
#pragma unroll
        for (int j = 0; j < 8; ++j) {
            int li = lset * 8 + j;
            int l = l0 + li;
            float xv = convd(z, blb, l, cxv, wxv, bxv) * mask[blb + l];
            xv_s[li][h] = xv;
            float gp = convd(z, blb, l, cg, wg, bg);
            gate_s[li][h] = gp / (1.f + __expf(-gp));
        }
    }
    __syncthreads();

    int h0 = lane >> 2, h1 = 16 + (lane >> 2), m = lane & 3;
    int hout = lane & 31;

    size_t o = ((size_t)(bk * NC_ + nc)) * 128;
    float are0 = cs_re[o + lane];
    float are1 = cs_re[o + 64 + lane];
    float aim0 = cs_im[o + lane];
    float aim1 = cs_im[o + 64 + lane];
    float den = cs_den[bk * NC_ + nc];
    float u = u_prev[((size_t)(bk * NC_ + nc)) * 32 + hout];

    // --- phase A: serial accumulate, per-lane s snapshots (no cross-lane) ---
    float sloc[CL_];
#pragma unroll
    for (int i = 0; i < CL_; ++i) {
        float th = theta_s[i * 4 + m];
        float pw = pw_s[i];
        float phi0 = xv_s[i][h0] * th;
        float phi1 = xv_s[i][h1] * th;
        float s0 = __sinf(phi0), cv0 = __cosf(phi0);
        float s1 = __sinf(phi1), cv1 = __cosf(phi1);
        float cre0 = b2f(f2bu(pw * cv0)), cim0 = b2f(f2bu(pw * s0));
        float cre1 = b2f(f2bu(pw * cv1)), cim1 = b2f(f2bu(pw * s1));
        are0 += cre0; aim0 += cim0; are1 += cre1; aim1 += cim1;
        sloc[i] = are0 * are0 + are1 * are1 + aim0 * aim0 + aim1 * aim1;
    }
    // --- phase B: 16 independent cross-lane reductions (pipelined) ---
#pragma unroll
    for (int i = 0; i < CL_; ++i) {
#pragma unroll
        for (int off = 32; off; off >>= 1) sloc[i] += __shfl_xor(sloc[i], off, 64);
    }
    // --- phase C: den/u chains + gate + store ---
#pragma unroll
    for (int i = 0; i < CL_; ++i) {
        int l = l0 + i;
        den += pw_s[i];
        float inv = 1.f / fmaxf(den, 1e-4f);
        float rsq = rsqrtf(inv * inv * sloc[i] * (1.0f / 256.0f) + 1e-5f);
        u += vc[(bkL + l) * 32 + hout];
        float gv = inv * rsq * u * gate_s[i][hout];
        if (lane < 32) gq[(size_t)(blb + l) * D_ + k * H_ + hout] = f2bu(gv);
    }
}

extern "C" void kernel_launch(void* const* d_in, const int* in_sizes, int n_in,
                              void* d_out, int out_size, void* d_ws, size_t ws_size,
                              hipStream_t stream) {
    const float* x = (const float*)d_in[0];
    const float* mask = (const float*)d_in[1];
    const float* W_in = (const float*)d_in[2];
    const float* conv_w = (const float*)d_in[3];
    const float* conv_b = (const float*)d_in[4];
    const float* theta_base = (const float*)d_in[5];
    const float* trs = (const float*)d_in[6];
    const float* dsl = (const float*)d_in[7];
    const float* asl = (const float*)d_in[8];
    const float* ssc = (const float*)d_in[9];
    const float* nsc = (const float*)d_in[10];
    const float* Wre = (const float*)d_in[11];
    const float* Wim = (const float*)d_in[12];
    const float* Wout = (const float*)d_in[13];
    float* out = (float*)d_out;

    char* ws = (char*)d_ws;
    ushort* z     = (ushort*)(ws);                   // 18,874,368
    ushort* Wt_in = (ushort*)(ws + 18874368ULL);     // 4,718,592
    ushort* Wt_o  = (ushort*)(ws + 23592960ULL);     // 2,097,152
    ushort* W2B   = (ushort*)(ws + 25690112ULL);     // 16,384
    float* vc     = (float*)(ws + 25706496ULL);      // 16,777,216
    float* cs_re  = (float*)(ws + 42483712ULL);      // 4,194,304
    float* cs_im  = (float*)(ws + 46678016ULL);      // 4,194,304
    float* cs_den = (float*)(ws + 50872320ULL);      // 32,768
    float* ucs    = (float*)(ws + 50905088ULL);      // 1,048,576
    float* u_prev = (float*)(ws + 51953664ULL);      // 1,048,576
    ushort* gq    = (ushort*)(ws + 53002240ULL);     // 8,388,608 (ends 61,390,848)

    prep_all<<<576 + 256 + 1, 256, 0, stream>>>(W_in, Wout, Wre, Wim, nsc,
                                                Wt_in, Wt_o, W2B);
    gemm_f32a<<<dim3(NPAD_ / 128, BL_ / 64), 256, 0, stream>>>(x, Wt_in, z, 1024, NPAD_);
    pass1f<<<dim3(NC_, K_, B_), 128, 0, stream>>>(z, mask, theta_base, trs, dsl, asl, ssc,
                                                  conv_w, conv_b, W2B,
                                                  cs_re, cs_im, cs_den, vc, ucs);
    scan2<<<73, 256, 0, stream>>>(cs_re, cs_im, cs_den, ucs, u_prev);
    scan_k7<<<dim3(NC_, K_, B_), 64, 0, stream>>>(z, mask, theta_base, trs, dsl, asl, ssc,
                                                  conv_w, conv_b, cs_re, cs_im, cs_den,
                                                  u_prev, vc, gq);
    gemm_bt64<<<dim3(1024 / 128, BL_ / 64), 256, 0, stream>>>(gq, Wt_o, out, 1024, 1024);
}

// Round 13
// 254.631 us; speedup vs baseline: 3.3708x; 1.0336x over previous
//
#include <hip/hip_runtime.h>
#include <hip/hip_bf16.h>
#include <math.h>

#define B_ 2
#define L_ 2048
#define D_ 1024
#define K_ 32
#define M_ 4
#define H_ 32
#define AH_ 4
#define DH_ 28
#define CK_ 4
#define TOTAL_ 2208
#define NPAD_ 2304
#define BL_ (B_*L_)
#define CL_ 16
#define NC_ (L_/CL_)   // 128
#define CTS_ 280       // ct row stride (ushorts)

typedef __attribute__((ext_vector_type(8))) short bf16x8;
typedef __attribute__((ext_vector_type(4))) float f32x4;

static __device__ inline unsigned short f2bu(float f) {
    union { __hip_bfloat16 h; unsigned short u; } cv;
    cv.h = __float2bfloat16(f);
    return cv.u;
}
static __device__ inline float b2f(unsigned short u) {
    union { unsigned short u; __hip_bfloat16 h; } cv;
    cv.u = u;
    return __bfloat162float(cv.h);
}

// direct 4-tap causal conv at position l (identical chain in pass1f & scan_k7
// so recomputed values match bitwise). z is bf16 with row stride NPAD_.
static __device__ inline float convd(const ushort* z, int blbase, int l, int ch,
                                     const float* w4, float bias) {
    float acc = bias;
#pragma unroll
    for (int tap = 0; tap < 4; ++tap) {
        int ls = l - 3 + tap;
        float zv = (ls >= 0) ? b2f(z[(size_t)(blbase + ls) * NPAD_ + ch]) : 0.f;
        acc = fmaf(w4[tap], zv, acc);
    }
    return acc;
}

// ---------- fused prep: x->bf16, W_in^T, Wout^T, W2B -------------------------
__global__ __launch_bounds__(256) void prep_all(const float* __restrict__ x,
                                                const float* __restrict__ W_in,
                                                const float* __restrict__ Wout,
                                                const float* __restrict__ Wre,
                                                const float* __restrict__ Wim,
                                                const float* __restrict__ nscale,
                                                ushort* __restrict__ x_bf,
                                                ushort* __restrict__ Wt_in,
                                                ushort* __restrict__ Wt_o,
                                                ushort* __restrict__ W2B) {
    __shared__ float tile[64][65];
    int bid = blockIdx.x, t = threadIdx.x;
    if (bid < 4096) {
        int i = bid * 256 + t;
        float4 v = ((const float4*)x)[i];
        ushort4 o;
        o.x = f2bu(v.x); o.y = f2bu(v.y); o.z = f2bu(v.z); o.w = f2bu(v.w);
        *(ushort4*)(x_bf + (size_t)i * 4) = o;
        return;
    }
    const float* src; ushort* dst; int Kd, N, n0, k0;
    if (bid < 4096 + 576) {
        int bb = bid - 4096;
        src = W_in; dst = Wt_in; Kd = 1024; N = TOTAL_;
        n0 = (bb % 36) * 64; k0 = (bb / 36) * 64;
    } else if (bid < 4096 + 576 + 256) {
        int bb = bid - 4096 - 576;
        src = Wout; dst = Wt_o; Kd = 1024; N = 1024;
        n0 = (bb % 16) * 64; k0 = (bb / 16) * 64;
    } else {
        int ch = t;  // 256
        float ns = nscale[ch];
        for (int ho = 0; ho < 32; ++ho) {
            float w = (ch < 128) ? Wre[ch * 32 + ho] : Wim[(ch - 128) * 32 + ho];
            W2B[ho * 256 + ch] = f2bu(ns * w);
        }
        return;
    }
#pragma unroll
    for (int i = 0; i < 16; ++i) {
        int idx = t + i * 256;
        int r = idx >> 6, c = idx & 63;
        int gn = n0 + c;
        tile[r][c] = (gn < N) ? src[(size_t)(k0 + r) * N + gn] : 0.f;
    }
    __syncthreads();
#pragma unroll
    for (int i = 0; i < 16; ++i) {
        int idx = t + i * 256;
        int r = idx >> 6, c = idx & 63;
        dst[(size_t)(n0 + r) * Kd + k0 + c] = f2bu(tile[c][r]);
    }
}

// ---------- bf16 MFMA GEMM, 64(M)x128(N) tile, BK=64 (two-panel LDS) ---------
template <bool OUT_BF16>
__global__ __launch_bounds__(256) void gemm_bt64(const ushort* __restrict__ A,
                                                 const ushort* __restrict__ Bt,
                                                 void* __restrict__ Cv,
                                                 int Kd, int ldc) {
    __shared__ __align__(16) ushort SB[2][192 * 32];
    int tid = threadIdx.x;
    int wave = tid >> 6, lane = tid & 63;
    int quad = lane >> 4, l16 = lane & 15;
    int n0 = blockIdx.x * 128, m0 = blockIdx.y * 64;
    int wm = (wave & 1) * 32, wn = (wave >> 1) * 64;
    f32x4 acc[2][4];
#pragma unroll
    for (int i = 0; i < 2; ++i)
#pragma unroll
        for (int j = 0; j < 4; ++j) acc[i][j] = (f32x4){0.f, 0.f, 0.f, 0.f};

    int swzq = quad ^ (l16 & 3);

    for (int k0 = 0; k0 < Kd; k0 += 64) {
#pragma unroll
        for (int p = 0; p < 2; ++p)
#pragma unroll
            for (int i = 0; i < 3; ++i) {
                int s = i * 256 + tid;
                int row = s >> 2;
                int qg = (s & 3) ^ (row & 3);
                const ushort* g = (row < 64)
                    ? A + (size_t)(m0 + row) * Kd + k0 + p * 32 + qg * 8
                    : Bt + (size_t)(n0 + row - 64) * Kd + k0 + p * 32 + qg * 8;
                __builtin_amdgcn_global_load_lds(
                    (const __attribute__((address_space(1))) void*)g,
                    (__attribute__((address_space(3))) void*)(SB[p] + (size_t)s * 8),
                    16, 0, 0);
            }
        __syncthreads();
#pragma unroll
        for (int p = 0; p < 2; ++p) {
            bf16x8 af[2], bfr[4];
#pragma unroll
            for (int mi = 0; mi < 2; ++mi)
                af[mi] = *(const bf16x8*)(SB[p] + (size_t)(wm + mi * 16 + l16) * 32 + swzq * 8);
#pragma unroll
            for (int ni = 0; ni < 4; ++ni)
                bfr[ni] = *(const bf16x8*)(SB[p] + (size_t)(64 + wn + ni * 16 + l16) * 32 + swzq * 8);
#pragma unroll
            for (int mi = 0; mi < 2; ++mi)
#pragma unroll
                for (int ni = 0; ni < 4; ++ni)
                    acc[mi][ni] = __builtin_amdgcn_mfma_f32_16x16x32_bf16(af[mi], bfr[ni], acc[mi][ni], 0, 0, 0);
        }
        __syncthreads();
    }
#pragma unroll
    for (int mi = 0; mi < 2; ++mi)
#pragma unroll
        for (int ni = 0; ni < 4; ++ni)
#pragma unroll
            for (int r = 0; r < 4; ++r) {
                int gm = m0 + wm + mi * 16 + quad * 4 + r;
                int gn = n0 + wn + ni * 16 + l16;
                if (OUT_BF16)
                    ((ushort*)Cv)[(size_t)gm * ldc + gn] = f2bu(acc[mi][ni][r]);
                else
                    ((float*)Cv)[(size_t)gm * ldc + gn] = acc[mi][ni][r];
            }
}

// ---------- pass1f: LDS precompute (theta/pw/xv) + chunk sums + vc MFMA ------
__global__ __launch_bounds__(128) void pass1f(const ushort* __restrict__ z,
                                              const float* __restrict__ mask,
                                              const float* __restrict__ theta_base,
                                              const float* __restrict__ trs_,
                                              const float* __restrict__ dslopes,
                                              const float* __restrict__ aslopes,
                                              const float* __restrict__ sscale_,
                                              const float* __restrict__ conv_w,
                                              const float* __restrict__ conv_b,
                                              const ushort* __restrict__ W2B,
                                              float* __restrict__ cs_re,
                                              float* __restrict__ cs_im,
                                              float* __restrict__ cs_den,
                                              float* __restrict__ vc,
                                              float* __restrict__ ucs) {
    __shared__ __align__(16) ushort ct[CL_ * CTS_];
    __shared__ float theta_s[CL_ * 4];
    __shared__ float pw_s[CL_];
    __shared__ float xv_s[CL_][33];

    int nc = blockIdx.x, k = blockIdx.y, b = blockIdx.z;
    int hm = threadIdx.x;
    int bk = b * K_ + k;
    size_t bkL = (size_t)bk * L_;
    int l0 = nc * CL_;
    int blb = b * L_;
    const float PI3 = 1.04719755119659775f;

    float raw = (k < DH_) ? dslopes[k] : aslopes[k - DH_];
    float slope = log1pf(__expf(raw));

    if (hm < 64) {
        int li = hm >> 2, m = hm & 3;
        int l = l0 + li;
        int cth = 2 * D_ + K_ + k * M_ + m;
        float wt[4];
#pragma unroll
        for (int t = 0; t < 4; ++t) wt[t] = conv_w[t * TOTAL_ + cth];
        float tr = convd(z, blb, l, cth, wt, conv_b[cth]);
        float td = tr / (1.f + fabsf(tr));
        theta_s[li * 4 + m] = theta_base[k * M_ + m] + trs_[k] * (td * PI3);
    }
    if (hm >= 64 && hm < 64 + CL_) {
        int li = hm - 64;
        int l = l0 + li;
        int csc = 2 * D_ + k;
        float wsv[4];
#pragma unroll
        for (int t = 0; t < 4; ++t) wsv[t] = conv_w[t * TOTAL_ + csc];
        float mval = mask[blb + l];
        float s_raw = convd(z, blb, l, csc, wsv, conv_b[csc]) * mval;
        float arg = fminf(fmaxf(sscale_[k] * s_raw, -20.f), 20.f);
        float p = __expf(arg) * mval;
        float tw = (k < DH_) ? __expf(-slope * (float)(L_ - 1 - l)) : __expf(-slope * (float)l);
        pw_s[li] = p * tw;
    }
    {
        int h = hm & 31, lset = hm >> 5;
        int cxv = k * H_ + h;
        float wxv[4];
#pragma unroll
        for (int t = 0; t < 4; ++t) wxv[t] = conv_w[t * TOTAL_ + cxv];
        float bxv = conv_b[cxv];
#pragma unroll
        for (int j = 0; j < 4; ++j) {
            int li = lset * 4 + j;
            int l = l0 + li;
            float xv = convd(z, blb, l, cxv, wxv, bxv) * mask[blb + l];
            xv_s[li][h] = xv;
        }
    }
    __syncthreads();

    int h = hm >> 2, m = hm & 3;
    float are = 0.f, aim = 0.f;
#pragma unroll
    for (int i = 0; i < CL_; ++i) {
        float phi = xv_s[i][h] * theta_s[i * 4 + m];
        float pw = pw_s[i];
        float sv = __sinf(phi), cv = __cosf(phi);
        unsigned short cu_re = f2bu(pw * cv);
        unsigned short cu_im = f2bu(pw * sv);
        are += b2f(cu_re); aim += b2f(cu_im);
        ct[i * CTS_ + hm] = cu_re;
        ct[i * CTS_ + 128 + hm] = cu_im;
    }
    size_t o = ((size_t)(bk * NC_ + nc)) * 128 + hm;
    cs_re[o] = are;
    cs_im[o] = aim;
    if (hm == 0) {
        float aden = 0.f;
#pragma unroll
        for (int i = 0; i < CL_; ++i) aden += pw_s[i];
        cs_den[bk * NC_ + nc] = aden;
    }
    __syncthreads();
    int wave = hm >> 6, lane = hm & 63;
    int quad = lane >> 4, l16 = lane & 15;
    f32x4 acc = (f32x4){0.f, 0.f, 0.f, 0.f};
#pragma unroll
    for (int ks = 0; ks < 8; ++ks) {
        bf16x8 af = *(const bf16x8*)(ct + (size_t)l16 * CTS_ + ks * 32 + quad * 8);
        bf16x8 bfr = *(const bf16x8*)(W2B + (size_t)(wave * 16 + l16) * 256 + ks * 32 + quad * 8);
        acc = __builtin_amdgcn_mfma_f32_16x16x32_bf16(af, bfr, acc, 0, 0, 0);
    }
    size_t vbase = (bkL + l0) * 32;
#pragma unroll
    for (int r = 0; r < 4; ++r) {
        int rowv = quad * 4 + r;
        vc[vbase + (size_t)rowv * 32 + wave * 16 + l16] = acc[r];
    }
    float part = acc[0] + acc[1] + acc[2] + acc[3];
    part += __shfl_xor(part, 16, 64);
    part += __shfl_xor(part, 32, 64);
    if (quad == 0) ucs[((size_t)(bk * NC_ + nc)) * 32 + wave * 16 + l16] = part;
}

// ---------- scan2: fused pass2 (cs exclusive scan) + u_prev scan -------------
__global__ void scan2(float* cs_re, float* cs_im, float* cs_den,
                      const float* __restrict__ ucs, float* __restrict__ u_prev) {
    int bid = blockIdx.x, tid = threadIdx.x;
    if (bid < 65) {
        int seq = bid * 256 + tid;
        if (seq >= B_ * K_ * 257) return;
        int bk = seq / 257;
        int ch = seq % 257;
        float* base;
        int stride;
        if (ch < 128) { base = cs_re + (size_t)bk * NC_ * 128 + ch; stride = 128; }
        else if (ch < 256) { base = cs_im + (size_t)bk * NC_ * 128 + (ch - 128); stride = 128; }
        else { base = cs_den + (size_t)bk * NC_; stride = 1; }
        float run = 0.f;
#pragma unroll 4
        for (int i = 0; i < NC_; ++i) {
            float v = base[(size_t)i * stride];
            base[(size_t)i * stride] = run;
            run += v;
        }
    } else {
        int idx = (bid - 65) * 256 + tid;  // 0..2047
        int hout = idx & 31;
        int bk = idx >> 5;
        float run = 0.f;
#pragma unroll 8
        for (int nc = 0; nc < NC_; ++nc) {
            size_t o = ((size_t)bk * NC_ + nc) * 32 + hout;
            float v = ucs[o];
            u_prev[o] = run;
            run += v;
        }
    }
}

// ---------- scan_k7: precompute + snapshot scan + deferred reduces + store ---
__global__ __launch_bounds__(64) void scan_k7(const ushort* __restrict__ z,
                                              const float* __restrict__ mask,
                                              const float* __restrict__ theta_base,
                                              const float* __restrict__ trs_,
                                              const float* __restrict__ dslopes,
                                              const float* __restrict__ aslopes,
                                              const float* __restrict__ sscale_,
                                              const float* __restrict__ conv_w,
                                              const float* __restrict__ conv_b,
                                              const float* __restrict__ cs_re,
                                              const float* __restrict__ cs_im,
                                              const float* __restrict__ cs_den,
                                              const float* __restrict__ u_prev,
                                              const float* __restrict__ vc,
                                              ushort* __restrict__ gq) {
    __shared__ float theta_s[CL_ * 4];
    __shared__ float pw_s[CL_];
    __shared__ float xv_s[CL_][33];
    __shared__ float gate_s[CL_][33];

    int nc = blockIdx.x, k = blockIdx.y, b = blockIdx.z;
    int lane = threadIdx.x;
    int bk = b * K_ + k;
    size_t bkL = (size_t)bk * L_;
    int l0 = nc * CL_;
    int blb = b * L_;
    const float PI3 = 1.04719755119659775f;

    float raw = (k < DH_) ? dslopes[k] : aslopes[k - DH_];
    float slope = log1pf(__expf(raw));

    {
        int li = lane >> 2, m = lane & 3;
        int l = l0 + li;
        int cth = 2 * D_ + K_ + k * M_ + m;
        float wt[4];
#pragma unroll
        for (int t = 0; t < 4; ++t) wt[t] = conv_w[t * TOTAL_ + cth];
        float tr = convd(z, blb, l, cth, wt, conv_b[cth]);
        float td = tr / (1.f + fabsf(tr));
        theta_s[li * 4 + m] = theta_base[k * M_ + m] + trs_[k] * (td * PI3);
    }
    if (lane < CL_) {
        int l = l0 + lane;
        int csc = 2 * D_ + k;
        float wsv[4];
#pragma unroll
        for (int t = 0; t < 4; ++t) wsv[t] = conv_w[t * TOTAL_ + csc];
        float mval = mask[blb + l];
        float s_raw = convd(z, blb, l, csc, wsv, conv_b[csc]) * mval;
        float arg = fminf(fmaxf(sscale_[k] * s_raw, -20.f), 20.f);
        float p = __expf(arg) * mval;
        float tw = (k < DH_) ? __expf(-slope * (float)(L_ - 1 - l)) : __expf(-slope * (float)l);
        pw_s[lane] = p * tw;
    }
    {
        int h = lane & 31, lset = lane >> 5;
        int cxv = k * H_ + h;
        int cg = D_ + k * H_ + h;
        float wxv[4], wg[4];
#pragma unroll
        for (int t = 0; t < 4; ++t) {
            wxv[t] = conv_w[t * TOTAL_ + cxv];
            wg[t] = conv_w[t * TOTAL_ + cg];
        }
        float bxv = conv_b[cxv], bg = conv_b[cg];
#pragma unroll
        for (int j = 0; j < 8; ++j) {
            int li = lset * 8 + j;
            int l = l0 + li;
            float xv = convd(z, blb, l, cxv, wxv, bxv) * mask[blb + l];
            xv_s[li][h] = xv;
            float gp = convd(z, blb, l, cg, wg, bg);
            gate_s[li][h] = gp / (1.f + __expf(-gp));
        }
    }
    __syncthreads();

    int h0 = lane >> 2, h1 = 16 + (lane >> 2), m = lane & 3;
    int hout = lane & 31;

    size_t o = ((size_t)(bk * NC_ + nc)) * 128;
    float are0 = cs_re[o + lane];
    float are1 = cs_re[o + 64 + lane];
    float aim0 = cs_im[o + lane];
    float aim1 = cs_im[o + 64 + lane];
    float den = cs_den[bk * NC_ + nc];
    float u = u_prev[((size_t)(bk * NC_ + nc)) * 32 + hout];

    // --- phase A: serial accumulate, per-lane s snapshots (no cross-lane) ---
    float sloc[CL_];
#pragma unroll
    for (int i = 0; i < CL_; ++i) {
        float th = theta_s[i * 4 + m];
        float pw = pw_s[i];
        float phi0 = xv_s[i][h0] * th;
        float phi1 = xv_s[i][h1] * th;
        float s0 = __sinf(phi0), cv0 = __cosf(phi0);
        float s1 = __sinf(phi1), cv1 = __cosf(phi1);
        float cre0 = b2f(f2bu(pw * cv0)), cim0 = b2f(f2bu(pw * s0));
        float cre1 = b2f(f2bu(pw * cv1)), cim1 = b2f(f2bu(pw * s1));
        are0 += cre0; aim0 += cim0; are1 += cre1; aim1 += cim1;
        sloc[i] = are0 * are0 + are1 * are1 + aim0 * aim0 + aim1 * aim1;
    }
    // --- phase B: 16 independent cross-lane reductions (pipelined) ---
#pragma unroll
    for (int i = 0; i < CL_; ++i) {
#pragma unroll
        for (int off = 32; off; off >>= 1) sloc[i] += __shfl_xor(sloc[i], off, 64);
    }
    // --- phase C: den/u chains + gate + store ---
#pragma unroll
    for (int i = 0; i < CL_; ++i) {
        int l = l0 + i;
        den += pw_s[i];
        float inv = 1.f / fmaxf(den, 1e-4f);
        float rsq = rsqrtf(inv * inv * sloc[i] * (1.0f / 256.0f) + 1e-5f);
        u += vc[(bkL + l) * 32 + hout];
        float gv = inv * rsq * u * gate_s[i][hout];
        if (lane < 32) gq[(size_t)(blb + l) * D_ + k * H_ + hout] = f2bu(gv);
    }
}

extern "C" void kernel_launch(void* const* d_in, const int* in_sizes, int n_in,
                              void* d_out, int out_size, void* d_ws, size_t ws_size,
                              hipStream_t stream) {
    const float* x = (const float*)d_in[0];
    const float* mask = (const float*)d_in[1];
    const float* W_in = (const float*)d_in[2];
    const float* conv_w = (const float*)d_in[3];
    const float* conv_b = (const float*)d_in[4];
    const float* theta_base = (const float*)d_in[5];
    const float* trs = (const float*)d_in[6];
    const float* dsl = (const float*)d_in[7];
    const float* asl = (const float*)d_in[8];
    const float* ssc = (const float*)d_in[9];
    const float* nsc = (const float*)d_in[10];
    const float* Wre = (const float*)d_in[11];
    const float* Wim = (const float*)d_in[12];
    const float* Wout = (const float*)d_in[13];
    float* out = (float*)d_out;

    char* ws = (char*)d_ws;
    ushort* z     = (ushort*)(ws);                   // 18,874,368
    ushort* x_bf  = (ushort*)(ws + 18874368ULL);     // 8,388,608
    ushort* Wt_in = (ushort*)(ws + 27262976ULL);     // 4,718,592
    ushort* Wt_o  = (ushort*)(ws + 31981568ULL);     // 2,097,152
    ushort* W2B   = (ushort*)(ws + 34078720ULL);     // 16,384
    float* vc     = (float*)(ws + 34095104ULL);      // 16,777,216
    float* cs_re  = (float*)(ws + 50872320ULL);      // 4,194,304
    float* cs_im  = (float*)(ws + 55066624ULL);      // 4,194,304
    float* cs_den = (float*)(ws + 59260928ULL);      // 32,768
    float* ucs    = (float*)(ws + 59293696ULL);      // 1,048,576
    float* u_prev = (float*)(ws + 60342272ULL);      // 1,048,576
    ushort* gq    = (ushort*)(ws + 61390848ULL);     // 8,388,608 (ends 69,779,456)

    prep_all<<<4096 + 576 + 256 + 1, 256, 0, stream>>>(x, W_in, Wout, Wre, Wim, nsc,
                                                       x_bf, Wt_in, Wt_o, W2B);
    gemm_bt64<true><<<dim3(NPAD_ / 128, BL_ / 64), 256, 0, stream>>>(x_bf, Wt_in, z, 1024, NPAD_);
    pass1f<<<dim3(NC_, K_, B_), 128, 0, stream>>>(z, mask, theta_base, trs, dsl, asl, ssc,
                                                  conv_w, conv_b, W2B,
                                                  cs_re, cs_im, cs_den, vc, ucs);
    scan2<<<73, 256, 0, stream>>>(cs_re, cs_im, cs_den, ucs, u_prev);
    scan_k7<<<dim3(NC_, K_, B_), 64, 0, stream>>>(z, mask, theta_base, trs, dsl, asl, ssc,
                                                  conv_w, conv_b, cs_re, cs_im, cs_den,
                                                  u_prev, vc, gq);
    gemm_bt64<false><<<dim3(1024 / 128, BL_ / 64), 256, 0, stream>>>(gq, Wt_o, out, 1024, 1024);
}